// Round 1
// baseline (1251.584 us; speedup 1.0000x reference)
//
#include <hip/hip_runtime.h>
#include <cmath>

// Problem constants (fixed by reference): B=8, N=2048, eps=0.01, 50 iters.
#define BATCH 8
#define NPT   2048
#define NPTS  (BATCH * NPT)
#define ROWS_PER_BLOCK 32
#define ROWS_PER_WAVE  8
#define TILES_PER_BATCH (NPT / ROWS_PER_BLOCK)   // 64
#define GRID_PASS (BATCH * TILES_PER_BATCH)      // 512

// exp(v_j - 100*cost) = exp2( C_LOG2E*v_j + NEG100C*(n_i + n_j) + S200C*dot )
#define C_LOG2E 1.4426950408889634f
#define NEG100C (-144.26950408889634f)   // -100 * log2(e)
#define S200C   288.53900817779268f      // 200 * log2(e)
#define EPS_LOG 1e-8f

static __device__ __forceinline__ float fast_exp2(float x) {
#if __has_builtin(__builtin_amdgcn_exp2f)
    return __builtin_amdgcn_exp2f(x);   // raw v_exp_f32
#else
    return exp2f(x);
#endif
}

// ---------------------------------------------------------------------------
// Setup: build augmented point arrays, zero u/v and emd output.
//  rawX[p] = (x, y, z, n)            n = |x|^2
//  sclX[p] = (x*S200C, y*S200C, z*S200C, n*NEG100C)
// ---------------------------------------------------------------------------
__global__ void setup_kernel(const float* __restrict__ x1,
                             const float* __restrict__ x2,
                             float4* __restrict__ r1, float4* __restrict__ s1,
                             float4* __restrict__ r2, float4* __restrict__ s2,
                             float* __restrict__ u, float* __restrict__ v,
                             float* __restrict__ emd) {
    int p = blockIdx.x * blockDim.x + threadIdx.x;
    if (p < NPTS) {
        float a = x1[3 * p + 0], b = x1[3 * p + 1], c = x1[3 * p + 2];
        float n = a * a + b * b + c * c;
        r1[p] = make_float4(a, b, c, n);
        s1[p] = make_float4(a * S200C, b * S200C, c * S200C, n * NEG100C);
        a = x2[3 * p + 0]; b = x2[3 * p + 1]; c = x2[3 * p + 2];
        n = a * a + b * b + c * c;
        r2[p] = make_float4(a, b, c, n);
        s2[p] = make_float4(a * S200C, b * S200C, c * S200C, n * NEG100C);
        u[p] = 0.0f;
        v[p] = 0.0f;
    }
    if (p < BATCH) emd[p] = 0.0f;
}

// ---------------------------------------------------------------------------
// One Sinkhorn half-step (symmetric in row/col roles):
//   out_i = log_mu - log( sum_j exp(dual_j - cost_ij/eps) + 1e-8 )
// rowRaw: (x,y,z,n) of row-side points; colScl: (xS,yS,zS,P) of col-side.
// ---------------------------------------------------------------------------
__global__ __launch_bounds__(256) void pass_kernel(
        const float4* __restrict__ rowRaw,
        const float4* __restrict__ colScl,
        const float*  __restrict__ dual,
        float*        __restrict__ out,
        float log_mu) {
    __shared__ float4 cd[NPT];   // 32 KB: (xS, yS, zS, P + log2e*dual)

    const int b    = blockIdx.x / TILES_PER_BATCH;
    const int tile = blockIdx.x % TILES_PER_BATCH;
    const int base = b * NPT;

    for (int j = threadIdx.x; j < NPT; j += 256) {
        float4 cs = colScl[base + j];
        cs.w = fmaf(C_LOG2E, dual[base + j], cs.w);
        cd[j] = cs;
    }
    __syncthreads();

    const int wave = threadIdx.x >> 6;
    const int lane = threadIdx.x & 63;
    const int row0 = tile * ROWS_PER_BLOCK + wave * ROWS_PER_WAVE;

    float rx[ROWS_PER_WAVE], ry[ROWS_PER_WAVE], rz[ROWS_PER_WAVE];
    float rc[ROWS_PER_WAVE], acc[ROWS_PER_WAVE];
#pragma unroll
    for (int r = 0; r < ROWS_PER_WAVE; r++) {
        float4 rd = rowRaw[base + row0 + r];   // wave-uniform broadcast load
        rx[r] = rd.x; ry[r] = rd.y; rz[r] = rd.z;
        rc[r] = rd.w * NEG100C;
        acc[r] = 0.0f;
    }

    for (int jc = 0; jc < NPT; jc += 64) {
        float4 y = cd[jc + lane];
#pragma unroll
        for (int r = 0; r < ROWS_PER_WAVE; r++) {
            float t = fmaf(rx[r], y.x, rc[r]);
            t = fmaf(ry[r], y.y, t);
            t = fmaf(rz[r], y.z, t);
            t += y.w;
            acc[r] += fast_exp2(t);
        }
    }

#pragma unroll
    for (int r = 0; r < ROWS_PER_WAVE; r++) {
        float s = acc[r];
#pragma unroll
        for (int m = 32; m >= 1; m >>= 1) s += __shfl_xor(s, m, 64);
        if (lane == r) out[base + row0 + r] = log_mu - logf(s + EPS_LOG);
    }
}

// ---------------------------------------------------------------------------
// Final: emd[b] = sum_ij exp(u_i + v_j - cost/eps) * cost
// ---------------------------------------------------------------------------
__global__ __launch_bounds__(256) void final_kernel(
        const float4* __restrict__ rowRaw,   // x1 side (x,y,z,n1)
        const float4* __restrict__ colRaw,   // x2 side (x,y,z,n2)
        const float*  __restrict__ u,
        const float*  __restrict__ v,
        float*        __restrict__ emd) {
    __shared__ float4 cd[NPT];   // (x2, y2, z2, cc_j = -100c*n2 + c*v_j)
    __shared__ float  cn[NPT];   // n2_j
    __shared__ float  wsum[4];

    const int b    = blockIdx.x / TILES_PER_BATCH;
    const int tile = blockIdx.x % TILES_PER_BATCH;
    const int base = b * NPT;

    for (int j = threadIdx.x; j < NPT; j += 256) {
        float4 c = colRaw[base + j];
        cn[j] = c.w;
        float cc = fmaf(C_LOG2E, v[base + j], c.w * NEG100C);
        cd[j] = make_float4(c.x, c.y, c.z, cc);
    }
    __syncthreads();

    const int wave = threadIdx.x >> 6;
    const int lane = threadIdx.x & 63;
    const int row0 = tile * ROWS_PER_BLOCK + wave * ROWS_PER_WAVE;

    float rx[ROWS_PER_WAVE], ry[ROWS_PER_WAVE], rz[ROWS_PER_WAVE];
    float rn[ROWS_PER_WAVE], rcc[ROWS_PER_WAVE];
#pragma unroll
    for (int r = 0; r < ROWS_PER_WAVE; r++) {
        float4 rd = rowRaw[base + row0 + r];
        rx[r] = rd.x; ry[r] = rd.y; rz[r] = rd.z;
        rn[r] = rd.w;
        rcc[r] = fmaf(C_LOG2E, u[base + row0 + r], rd.w * NEG100C);
    }

    float eacc = 0.0f;
    for (int jc = 0; jc < NPT; jc += 64) {
        float4 y = cd[jc + lane];
        float n2 = cn[jc + lane];
#pragma unroll
        for (int r = 0; r < ROWS_PER_WAVE; r++) {
            float dot = rx[r] * y.x;
            dot = fmaf(ry[r], y.y, dot);
            dot = fmaf(rz[r], y.z, dot);
            float cost = fmaf(-2.0f, dot, rn[r] + n2);
            float t = fmaf(S200C, dot, rcc[r] + y.w);
            eacc = fmaf(fast_exp2(t), cost, eacc);
        }
    }

#pragma unroll
    for (int m = 32; m >= 1; m >>= 1) eacc += __shfl_xor(eacc, m, 64);
    if (lane == 0) wsum[wave] = eacc;
    __syncthreads();
    if (threadIdx.x == 0) {
        float s = wsum[0] + wsum[1] + wsum[2] + wsum[3];
        atomicAdd(&emd[b], s);
    }
}

// ---------------------------------------------------------------------------
extern "C" void kernel_launch(void* const* d_in, const int* in_sizes, int n_in,
                              void* d_out, int out_size, void* d_ws, size_t ws_size,
                              hipStream_t stream) {
    (void)in_sizes; (void)n_in; (void)out_size; (void)ws_size;
    const float* x1 = (const float*)d_in[0];
    const float* x2 = (const float*)d_in[1];
    float* out = (float*)d_out;

    char* ws = (char*)d_ws;
    float4* r1 = (float4*)ws;            // NPTS float4
    float4* s1 = r1 + NPTS;
    float4* r2 = s1 + NPTS;
    float4* s2 = r2 + NPTS;
    float* u = (float*)(s2 + NPTS);      // NPTS floats
    float* v = u + NPTS;                 // NPTS floats

    const float log_mu = logf(1.0f / (float)NPT + EPS_LOG);  // == log_nu

    setup_kernel<<<(NPTS + 255) / 256, 256, 0, stream>>>(x1, x2, r1, s1, r2, s2,
                                                         u, v, out);
    for (int it = 0; it < 50; it++) {
        // u = log_mu - log(sum_j K_ij exp(v_j) + eps)
        pass_kernel<<<GRID_PASS, 256, 0, stream>>>(r1, s2, v, u, log_mu);
        // v = log_nu - log(sum_i K_ij exp(u_i) + eps)
        pass_kernel<<<GRID_PASS, 256, 0, stream>>>(r2, s1, u, v, log_mu);
    }
    final_kernel<<<GRID_PASS, 256, 0, stream>>>(r1, r2, u, v, out);
}